// Round 16
// baseline (78.876 us; speedup 1.0000x reference)
//
#include <hip/hip_runtime.h>

#define T_ 1000
#define B_ 64
#define V_ 1024
#define NEGF (-1e30f)
#define LOG2E_ 1.4426950408889634f
#define LN2_ 0.6931471805599453f
// Q3(u) ~= log2(1+u), u in [0,1]; Q3(1)=1 exact; |err| <= ~3e-3
#define P0C 1.4405f
#define P1C (-0.64178f)
#define P2C 0.20128f

__device__ __forceinline__ float ex2(float x) { return __builtin_amdgcn_exp2f(x); }
__device__ __forceinline__ float lg2(float x) { return __builtin_amdgcn_logf(x); }
__device__ __forceinline__ float rlane(float x, int l) {
    return __int_as_float(__builtin_amdgcn_readlane(__float_as_int(x), l));
}
#define FENCE_ __builtin_amdgcn_sched_barrier(0)

// In-wave target setup (B_ == 64 == wave): lane l gets tgt[l] of sample b, plus L.
__device__ __forceinline__ void load_tgt(const int* __restrict__ targets,
                                         const int* __restrict__ tlen,
                                         int b, int lane, int& tg, int& L) {
    int tl = tlen[lane];
    L = __shfl(tl, b);
    int v = (lane < b) ? tl : 0;
    for (int off = 32; off; off >>= 1) v += __shfl_xor(v, off);  // offset_b (uniform)
    tg = (lane < L) ? targets[v + lane] : 0;
}

// Fused fwd+bwd CTC in ONE wave per sample: the two independent serial chains
// are interleaved in the issue stream so each hides the other's ALU latency.
// Lane i owns states 2i/2i+1; lane 63's label slot = BLANK. alpha to t=M,
// beta from Te down to M+1; junction -> aw[b][4][64].
__global__ __launch_bounds__(64) void ctc_fb2_k(const float* __restrict__ lp,
                                                const int* __restrict__ targets,
                                                const int* __restrict__ tlen,
                                                const int* __restrict__ ilen,
                                                float* __restrict__ aw) {
    int b = blockIdx.x, lane = threadIdx.x;
    int tg, L;
    load_tgt(targets, tlen, b, lane, tg, L);
    int Tin = ilen[b], Te = Tin - 1;
    int M = Te >> 1;
    int K = Te - M;                            // bwd consumes k=0..K-1 (t = Te-k)
    int tgp = __shfl_up(tg, 1);
    bool skip1 = (lane >= 1) && (tg != 0) && (tg != tgp);
    int col = (lane == 63) ? 0 : tg;
    int idx = (b << 10) + col;                 // element offset within a t-slab
    float* awb = aw + b * 256;

    bool is16 = (lane == 16), is32 = (lane == 32), is48 = (lane == 48);
    bool is15 = (lane == 15), is31 = (lane == 31), is47 = (lane == 47);

    float a0 = NEGF, a1 = NEGF;                // fwd state
    float B0 = (lane == L) ? 0.0f : NEGF;      // bwd state 2L
    float B1 = (L > 0 && lane == L - 1) ? 0.0f : NEGF;  // state 2L-1

    auto ldF = [&](int g, float4& S) {         // fwd: t ascending, clamped to M
        int t0 = 4 * g;
        int ta = t0 < M ? t0 : M, tb2 = t0 + 1 < M ? t0 + 1 : M;
        int tc = t0 + 2 < M ? t0 + 2 : M, td = t0 + 3 < M ? t0 + 3 : M;
        S.x = (lp + ((size_t)ta << 16))[idx];
        S.y = (lp + ((size_t)tb2 << 16))[idx];
        S.z = (lp + ((size_t)tc << 16))[idx];
        S.w = (lp + ((size_t)td << 16))[idx];
    };
    auto ldB = [&](int g, float4& S) {         // bwd: t descending, clamped to 0
        int t0 = Te - 4 * g;
        int ta = t0 > 0 ? t0 : 0, tb2 = t0 - 1 > 0 ? t0 - 1 : 0;
        int tc = t0 - 2 > 0 ? t0 - 2 : 0, td = t0 - 3 > 0 ? t0 - 3 : 0;
        S.x = (lp + ((size_t)ta << 16))[idx];
        S.y = (lp + ((size_t)tb2 << 16))[idx];
        S.z = (lp + ((size_t)tc << 16))[idx];
        S.w = (lp + ((size_t)td << 16))[idx];
    };
    auto shr1 = [&](float x) -> float {        // lane i <- x[i-1]; lane 0 <- NEGF
        float v15 = rlane(x, 15), v31 = rlane(x, 31), v47 = rlane(x, 47);
        float bval = is16 ? v15 : (is32 ? v31 : (is48 ? v47 : NEGF));
        return __int_as_float(__builtin_amdgcn_update_dpp(
            __float_as_int(bval), __float_as_int(x), 0x111, 0xF, 0xF, false));
    };
    auto shl1 = [&](float x) -> float {        // lane i <- x[i+1]; lane 63 <- NEGF
        float v16 = rlane(x, 16), v32 = rlane(x, 32), v48 = rlane(x, 48);
        float bval = is15 ? v16 : (is31 ? v32 : (is47 ? v48 : NEGF));
        return __int_as_float(__builtin_amdgcn_update_dpp(
            __float_as_int(bval), __float_as_int(x), 0x101, 0xF, 0xF, false));
    };
    auto step = [&](float xb, float xe) {      // fwd (champion numerics)
        float p1m = shr1(a1);
        float d0 = a0 - p1m;
        float m0 = fmaxf(a0, p1m);
        float u = ex2(-fabsf(d0));
        float h = fmaf(u, P2C, P1C);
        h = fmaf(u, h, P0C);
        float U = fmaf(u, h, m0);              // lae(a0, p1m)
        float na0 = U + xb;
        float w = skip1 ? U : a0;
        float d1 = a1 - w;
        float m1 = fmaxf(a1, w);
        float v = ex2(-fabsf(d1));
        float h1 = fmaf(v, P2C, P1C);
        h1 = fmaf(v, h1, P0C);
        float na1 = fmaf(v, h1, m1 + xe);
        a0 = na0; a1 = na1;
    };
    auto stepb = [&](float xb, float xe) {     // bwd (champion numerics)
        float z = B1 + xe;
        float t0v = B0 + xb;
        float d0 = t0v - z;
        float m0 = fmaxf(t0v, z);
        float u = ex2(-fabsf(d0));
        float h = fmaf(u, P2C, P1C);
        h = fmaf(u, h, P0C);
        float B0n = fmaf(u, h, m0);            // lae2(t0v, z)
        float y = skip1 ? B0n : t0v;
        float arg = shl1(y);
        float d1 = z - arg;
        float m1 = fmaxf(z, arg);
        float v = ex2(-fabsf(d1));
        float h1 = fmaf(v, P2C, P1C);
        h1 = fmaf(v, h1, P0C);
        float B1n = fmaf(v, h1, m1);           // lae2(z, arg)
        B0 = B0n; B1 = B1n;
    };

    if (M >= 35) {
        float4 F0, F1, F2, F3, F4, F5, F6, F7;
        float4 R0, R1, R2, R3, R4, R5, R6, R7;
        ldF(0, F0); ldB(0, R0); ldF(1, F1); ldB(1, R1);
        ldF(2, F2); ldB(2, R2); ldF(3, F3); ldB(3, R3);
        ldF(4, F4); ldB(4, R4); ldF(5, F5); ldB(5, R5);
        ldF(6, F6); ldB(6, R6); ldF(7, F7); ldB(7, R7);
        FENCE_;
        {   // group 0: fwd init + t=1..3, bwd k=0..3 (interleavable chains)
            float f0 = F0.x * LOG2E_, f1 = F0.y * LOG2E_;
            float f2 = F0.z * LOG2E_, f3 = F0.w * LOG2E_;
            float g0 = R0.x * LOG2E_, g1 = R0.y * LOG2E_;
            float g2 = R0.z * LOG2E_, g3 = R0.w * LOG2E_;
            a0 = (lane == 0) ? rlane(f0, 63) : NEGF;
            a1 = (lane == 0 && L > 0) ? f0 : NEGF;
            step(rlane(f1, 63), f1); stepb(rlane(g0, 63), g0);
            step(rlane(f2, 63), f2); stepb(rlane(g1, 63), g1);
            step(rlane(f3, 63), f3); stepb(rlane(g2, 63), g2);
            stepb(rlane(g3, 63), g3);
            ldF(8, F0); ldB(8, R0);
            FENCE_;
        }
#define COMB(F, R, G) do {                                                     \
        float f0_ = F.x * LOG2E_, f1_ = F.y * LOG2E_;                          \
        float f2_ = F.z * LOG2E_, f3_ = F.w * LOG2E_;                          \
        float g0_ = R.x * LOG2E_, g1_ = R.y * LOG2E_;                          \
        float g2_ = R.z * LOG2E_, g3_ = R.w * LOG2E_;                          \
        float fb0_ = rlane(f0_, 63), fb1_ = rlane(f1_, 63);                    \
        float fb2_ = rlane(f2_, 63), fb3_ = rlane(f3_, 63);                    \
        float gb0_ = rlane(g0_, 63), gb1_ = rlane(g1_, 63);                    \
        float gb2_ = rlane(g2_, 63), gb3_ = rlane(g3_, 63);                    \
        step(fb0_, f0_); stepb(gb0_, g0_);                                     \
        step(fb1_, f1_); stepb(gb1_, g1_);                                     \
        step(fb2_, f2_); stepb(gb2_, g2_);                                     \
        step(fb3_, f3_); stepb(gb3_, g3_);                                     \
        ldF((G) + 8, F); ldB((G) + 8, R);                                      \
        FENCE_;                                                                \
    } while (0)
        COMB(F1, R1, 1); COMB(F2, R2, 2); COMB(F3, R3, 3);
        COMB(F4, R4, 4); COMB(F5, R5, 5); COMB(F6, R6, 6); COMB(F7, R7, 7);
        int mn = (M < K - 1) ? M : (K - 1);
        int c = 1;
        for (; 32 * c + 31 <= mn; ++c) {
            int g0 = 8 * c;
            COMB(F0, R0, g0 + 0); COMB(F1, R1, g0 + 1);
            COMB(F2, R2, g0 + 2); COMB(F3, R3, g0 + 3);
            COMB(F4, R4, g0 + 4); COMB(F5, R5, g0 + 5);
            COMB(F6, R6, g0 + 6); COMB(F7, R7, g0 + 7);
        }
#undef COMB
        int tb = 32 * c;
#define TAILC(F, R, T0) do {                                                   \
        float f0_ = F.x * LOG2E_, f1_ = F.y * LOG2E_;                          \
        float f2_ = F.z * LOG2E_, f3_ = F.w * LOG2E_;                          \
        float g0_ = R.x * LOG2E_, g1_ = R.y * LOG2E_;                          \
        float g2_ = R.z * LOG2E_, g3_ = R.w * LOG2E_;                          \
        if ((T0) + 0 <= M) step(rlane(f0_, 63), f0_);                          \
        if ((T0) + 0 <= K - 1) stepb(rlane(g0_, 63), g0_);                     \
        if ((T0) + 1 <= M) step(rlane(f1_, 63), f1_);                          \
        if ((T0) + 1 <= K - 1) stepb(rlane(g1_, 63), g1_);                     \
        if ((T0) + 2 <= M) step(rlane(f2_, 63), f2_);                          \
        if ((T0) + 2 <= K - 1) stepb(rlane(g2_, 63), g2_);                     \
        if ((T0) + 3 <= M) step(rlane(f3_, 63), f3_);                          \
        if ((T0) + 3 <= K - 1) stepb(rlane(g3_, 63), g3_);                     \
    } while (0)
        TAILC(F0, R0, tb + 0);  TAILC(F1, R1, tb + 4);
        TAILC(F2, R2, tb + 8);  TAILC(F3, R3, tb + 12);
        TAILC(F4, R4, tb + 16); TAILC(F5, R5, tb + 20);
        TAILC(F6, R6, tb + 24); TAILC(F7, R7, tb + 28);
#undef TAILC
    } else if (Tin >= 1) {
        // small-Te safety path (never hit: Tin >= 500)
        float e = lp[idx] * LOG2E_;
        a0 = (lane == 0) ? rlane(e, 63) : NEGF;
        a1 = (lane == 0 && L > 0) ? e : NEGF;
        for (int t = 1; t <= M; ++t) {
            float xe = (lp + ((size_t)t << 16))[idx] * LOG2E_;
            step(rlane(xe, 63), xe);
        }
        for (int k = 0; k < K; ++k) {
            int t = Te - k;
            float xe = (lp + ((size_t)t << 16))[idx] * LOG2E_;
            stepb(rlane(xe, 63), xe);
        }
    }

    awb[lane] = a0;
    awb[64 + lane] = a1;
    awb[128 + lane] = B0;
    awb[192 + lane] = B1;
}

// Per-sample junction combine: fin = lae over 128 states of (alpha_M + beta_M).
__global__ __launch_bounds__(64) void combine_k(const float* __restrict__ aw,
                                                const int* __restrict__ tlen,
                                                const int* __restrict__ ilen,
                                                float* __restrict__ losses) {
    int b = blockIdx.x, lane = threadIdx.x;
    const float* awb = aw + b * 256;
    float s0 = awb[lane] + awb[128 + lane];
    float s1 = awb[64 + lane] + awb[192 + lane];
    float m = fmaxf(s0, s1);
    for (int off = 32; off; off >>= 1) m = fmaxf(m, __shfl_xor(m, off));
    float sum = ex2(s0 - m) + ex2(s1 - m);
    for (int off = 32; off; off >>= 1) sum += __shfl_xor(sum, off);
    if (lane == 0) {
        int L = tlen[b];
        float fin = lg2(sum) + m;                  // log2 domain
        if (ilen[b] <= 0) fin = NEGF;
        float loss = (L > 0) ? -fin * LN2_ : 0.0f;
        if (!(loss < 1e29f)) loss = 0.0f;          // zero_infinity (NaN-safe)
        losses[b] = loss;
    }
}

// Fallback when ws too small: fully serial per-sample forward straight from lp.
__global__ __launch_bounds__(64) void ctc_rec_direct_k(const float* __restrict__ lp,
                                                       const int* __restrict__ targets,
                                                       const int* __restrict__ tlen,
                                                       const int* __restrict__ ilen,
                                                       float* __restrict__ losses) {
    int b = blockIdx.x, lane = threadIdx.x;
    int tg, L;
    load_tgt(targets, tlen, b, lane, tg, L);
    int Tin = ilen[b], Te = Tin - 1;
    int tgp = __shfl_up(tg, 1);
    bool skip1 = (lane >= 1) && (tg != 0) && (tg != tgp);
    bool is16 = (lane == 16), is32 = (lane == 32), is48 = (lane == 48);
    int col = (lane == 63) ? 0 : tg;
    int idx = (b << 10) + col;
    float a0 = NEGF, a1 = NEGF;
    auto shr1 = [&](float x) -> float {
        float v15 = rlane(x, 15), v31 = rlane(x, 31), v47 = rlane(x, 47);
        float bval = is16 ? v15 : (is32 ? v31 : (is48 ? v47 : NEGF));
        return __int_as_float(__builtin_amdgcn_update_dpp(
            __float_as_int(bval), __float_as_int(x), 0x111, 0xF, 0xF, false));
    };
    auto step = [&](float xb, float xe) {
        float p1m = shr1(a1);
        float d0 = a0 - p1m;
        float m0 = fmaxf(a0, p1m);
        float u = ex2(-fabsf(d0));
        float h = fmaf(u, P2C, P1C);
        h = fmaf(u, h, P0C);
        float U = fmaf(u, h, m0);
        float na0 = U + xb;
        float w = skip1 ? U : a0;
        float d1 = a1 - w;
        float m1 = fmaxf(a1, w);
        float v = ex2(-fabsf(d1));
        float h1 = fmaf(v, P2C, P1C);
        h1 = fmaf(v, h1, P0C);
        float na1 = fmaf(v, h1, m1 + xe);
        a0 = na0; a1 = na1;
    };
    if (Tin >= 1) {
        float e = lp[idx] * LOG2E_;
        a0 = (lane == 0) ? rlane(e, 63) : NEGF;
        a1 = (lane == 0 && L > 0) ? e : NEGF;
        for (int t = 1; t <= Te; ++t) {
            float xe = (lp + ((size_t)t << 16))[idx] * LOG2E_;
            step(rlane(xe, 63), xe);
        }
    }
    int lidx = (L > 0) ? (L - 1) : 0;
    float aPrev = __shfl(a1, lidx);
    float aLast = __shfl(a0, (L < 63) ? L : 63);
    float x = aLast, y = (L > 0) ? aPrev : NEGF;
    float m = fmaxf(x, y), d = fminf(x, y) - m;
    float fin = m + lg2(1.0f + ex2(d));
    if (Tin <= 0) fin = NEGF;
    if (lane == 0) {
        float loss = (L > 0) ? -fin * LN2_ : 0.0f;
        if (!(loss < 1e29f)) loss = 0.0f;
        losses[b] = loss;
    }
}

__global__ __launch_bounds__(64) void finalize_k(const float* __restrict__ losses,
                                                 const int* __restrict__ gid,
                                                 float* __restrict__ out) {
    int lane = threadIdx.x;
    float l = losses[lane];
    int g = gid[lane];
    float s = l;
    float s0 = (g == 0) ? l : 0.0f, c0 = (g == 0) ? 1.0f : 0.0f;
    float s1 = (g == 1) ? l : 0.0f, c1 = (g == 1) ? 1.0f : 0.0f;
    for (int off = 32; off; off >>= 1) {
        s  += __shfl_xor(s, off);
        s0 += __shfl_xor(s0, off);
        c0 += __shfl_xor(c0, off);
        s1 += __shfl_xor(s1, off);
        c1 += __shfl_xor(c1, off);
    }
    if (lane == 0) {
        float base = s * (1.0f / B_);
        float m0 = s0 / fmaxf(c0, 1.0f);
        float m1 = s1 / fmaxf(c1, 1.0f);
        float mean = 0.5f * (m0 + m1);
        float var = (m0 - mean) * (m0 - mean) + (m1 - mean) * (m1 - mean); // ddof=1, N=2
        out[0] = base + 0.5f * var;
        out[1] = base;
        out[2] = var;
    }
}

extern "C" void kernel_launch(void* const* d_in, const int* in_sizes, int n_in,
                              void* d_out, int out_size, void* d_ws, size_t ws_size,
                              hipStream_t stream) {
    const float* lp = (const float*)d_in[0];
    const int* targets = (const int*)d_in[1];
    const int* ilen = (const int*)d_in[2];
    const int* tlen = (const int*)d_in[3];
    const int* gid = (const int*)d_in[4];
    float* out = (float*)d_out;

    char* ws = (char*)d_ws;
    float* losses = (float*)ws;                       // 256 B
    float* aw = (float*)(ws + 1024);                  // 64*256*4 = 64 KB
    size_t need = 1024 + (size_t)B_ * 256 * 4;

    if (ws_size >= need) {
        ctc_fb2_k<<<B_, 64, 0, stream>>>(lp, targets, tlen, ilen, aw);
        combine_k<<<B_, 64, 0, stream>>>(aw, tlen, ilen, losses);
    } else {
        ctc_rec_direct_k<<<B_, 64, 0, stream>>>(lp, targets, tlen, ilen, losses);
    }
    finalize_k<<<1, 64, 0, stream>>>(losses, gid, out);
}

// Round 17
// 46.723 us; speedup vs baseline: 1.6882x; 1.6882x over previous
//
#include <hip/hip_runtime.h>

#define T_ 1000
#define B_ 64
#define V_ 1024
#define NEGF (-1e30f)
#define LOG2E_ 1.4426950408889634f
#define LN2_ 0.6931471805599453f
// Q3(u) ~= log2(1+u), u in [0,1]; Q3(1)=1 exact; |err| <= ~3e-3
#define P0C 1.4405f
#define P1C (-0.64178f)
#define P2C 0.20128f

__device__ __forceinline__ float ex2(float x) { return __builtin_amdgcn_exp2f(x); }
__device__ __forceinline__ float lg2(float x) { return __builtin_amdgcn_logf(x); }
__device__ __forceinline__ float rlane(float x, int l) {
    return __int_as_float(__builtin_amdgcn_readlane(__float_as_int(x), l));
}
#define FENCE_ __builtin_amdgcn_sched_barrier(0)

// In-wave target setup (B_ == 64 == wave): lane l gets tgt[l] of sample b, plus L.
__device__ __forceinline__ void load_tgt(const int* __restrict__ targets,
                                         const int* __restrict__ tlen,
                                         int b, int lane, int& tg, int& L) {
    int tl = tlen[lane];
    L = __shfl(tl, b);
    int v = (lane < b) ? tl : 0;
    for (int off = 32; off; off >>= 1) v += __shfl_xor(v, off);  // offset_b (uniform)
    tg = (lane < L) ? targets[v + lane] : 0;
}

// Fused fwd/bwd CTC, direct per-lane scattered loads from lp (8-group pipeline).
// Blocks 0..63: alpha forward to t=M (M=Te/2). Blocks 64..127: beta backward
// from Te down to M+1. Lane i owns states 2i/2i+1; lane 63's label slot = BLANK.
__global__ __launch_bounds__(64) void ctc_fb_k(const float* __restrict__ lp,
                                               const int* __restrict__ targets,
                                               const int* __restrict__ tlen,
                                               const int* __restrict__ ilen,
                                               float* __restrict__ aw) {
    int blk = blockIdx.x, lane = threadIdx.x;
    bool isFwd = blk < B_;
    int b = isFwd ? blk : blk - B_;
    int tg, L;
    load_tgt(targets, tlen, b, lane, tg, L);
    int Tin = ilen[b], Te = Tin - 1;
    int M = Te >> 1;
    int tgp = __shfl_up(tg, 1);
    bool skip1 = (lane >= 1) && (tg != 0) && (tg != tgp);
    int col = (lane == 63) ? 0 : tg;
    int idx = (b << 10) + col;                 // element offset within a t-slab
    float* awb = aw + b * 256;

    if (isFwd) {
        bool is16 = (lane == 16), is32 = (lane == 32), is48 = (lane == 48);
        float a0 = NEGF, a1 = NEGF;
        auto ldG = [&](int g, float4& S) {     // t ascending, clamped to M
            int t0 = 4 * g;
            int ta = t0 < M ? t0 : M, tb2 = t0 + 1 < M ? t0 + 1 : M;
            int tc = t0 + 2 < M ? t0 + 2 : M, td = t0 + 3 < M ? t0 + 3 : M;
            S.x = (lp + ((size_t)ta << 16))[idx];
            S.y = (lp + ((size_t)tb2 << 16))[idx];
            S.z = (lp + ((size_t)tc << 16))[idx];
            S.w = (lp + ((size_t)td << 16))[idx];
        };
        auto shr1 = [&](float x) -> float {    // lane i <- x[i-1]; lane 0 <- NEGF
            float v15 = rlane(x, 15), v31 = rlane(x, 31), v47 = rlane(x, 47);
            float bval = is16 ? v15 : (is32 ? v31 : (is48 ? v47 : NEGF));
            return __int_as_float(__builtin_amdgcn_update_dpp(
                __float_as_int(bval), __float_as_int(x), 0x111, 0xF, 0xF, false));
        };
        auto step = [&](float xb, float xe) {
            float p1m = shr1(a1);
            float d0 = a0 - p1m;
            float m0 = fmaxf(a0, p1m);
            float u = ex2(-fabsf(d0));
            float h = fmaf(u, P2C, P1C);
            h = fmaf(u, h, P0C);
            float U = fmaf(u, h, m0);          // lae(a0, p1m)
            float na0 = U + xb;
            float w = skip1 ? U : a0;
            float d1 = a1 - w;
            float m1 = fmaxf(a1, w);
            float v = ex2(-fabsf(d1));
            float h1 = fmaf(v, P2C, P1C);
            h1 = fmaf(v, h1, P0C);
            float na1 = fmaf(v, h1, m1 + xe);
            a0 = na0; a1 = na1;
        };
        if (M >= 35) {
            float4 S0, S1, S2, S3, S4, S5, S6, S7;
            ldG(0, S0); ldG(1, S1); ldG(2, S2); ldG(3, S3);
            ldG(4, S4); ldG(5, S5); ldG(6, S6); ldG(7, S7);
            FENCE_;
            {
                float e0 = S0.x * LOG2E_, e1 = S0.y * LOG2E_;
                float e2 = S0.z * LOG2E_, e3 = S0.w * LOG2E_;
                a0 = (lane == 0) ? rlane(e0, 63) : NEGF;
                a1 = (lane == 0 && L > 0) ? e0 : NEGF;
                step(rlane(e1, 63), e1); step(rlane(e2, 63), e2); step(rlane(e3, 63), e3);
                ldG(8, S0);
                FENCE_;
            }
#define SUBF_F(S, G) do {                                                      \
            float e0_ = S.x * LOG2E_, e1_ = S.y * LOG2E_;                      \
            float e2_ = S.z * LOG2E_, e3_ = S.w * LOG2E_;                      \
            float b0_ = rlane(e0_, 63), b1_ = rlane(e1_, 63);                  \
            float b2_ = rlane(e2_, 63), b3_ = rlane(e3_, 63);                  \
            step(b0_, e0_); step(b1_, e1_); step(b2_, e2_); step(b3_, e3_);    \
            ldG((G) + 8, S);                                                   \
            FENCE_;                                                            \
        } while (0)
            SUBF_F(S1, 1); SUBF_F(S2, 2); SUBF_F(S3, 3); SUBF_F(S4, 4);
            SUBF_F(S5, 5); SUBF_F(S6, 6); SUBF_F(S7, 7);
            int c = 1;
            for (; 32 * c + 31 <= M; ++c) {
                int g0 = 8 * c;
                SUBF_F(S0, g0 + 0); SUBF_F(S1, g0 + 1); SUBF_F(S2, g0 + 2); SUBF_F(S3, g0 + 3);
                SUBF_F(S4, g0 + 4); SUBF_F(S5, g0 + 5); SUBF_F(S6, g0 + 6); SUBF_F(S7, g0 + 7);
            }
#undef SUBF_F
            int tb = 32 * c;
#define SUBT_F(S, T0) do {                                                     \
            float e0_ = S.x * LOG2E_, e1_ = S.y * LOG2E_;                      \
            float e2_ = S.z * LOG2E_, e3_ = S.w * LOG2E_;                      \
            float b0_ = rlane(e0_, 63), b1_ = rlane(e1_, 63);                  \
            float b2_ = rlane(e2_, 63), b3_ = rlane(e3_, 63);                  \
            if ((T0) + 0 <= M) step(b0_, e0_);                                 \
            if ((T0) + 1 <= M) step(b1_, e1_);                                 \
            if ((T0) + 2 <= M) step(b2_, e2_);                                 \
            if ((T0) + 3 <= M) step(b3_, e3_);                                 \
        } while (0)
            SUBT_F(S0, tb + 0);  SUBT_F(S1, tb + 4);  SUBT_F(S2, tb + 8);  SUBT_F(S3, tb + 12);
            SUBT_F(S4, tb + 16); SUBT_F(S5, tb + 20); SUBT_F(S6, tb + 24); SUBT_F(S7, tb + 28);
#undef SUBT_F
        } else if (Tin >= 1) {
            float e = lp[idx] * LOG2E_;
            a0 = (lane == 0) ? rlane(e, 63) : NEGF;
            a1 = (lane == 0 && L > 0) ? e : NEGF;
            for (int t = 1; t <= M; ++t) {
                float xe = (lp + ((size_t)t << 16))[idx] * LOG2E_;
                step(rlane(xe, 63), xe);
            }
        }
        awb[lane] = a0;
        awb[64 + lane] = a1;
    } else {
        // ---------------- backward ----------------
        bool is15 = (lane == 15), is31 = (lane == 31), is47 = (lane == 47);
        int K = Te - M;                        // steps, consuming t = Te .. M+1
        float B0 = (lane == L) ? 0.0f : NEGF;
        float B1 = (L > 0 && lane == L - 1) ? 0.0f : NEGF;
        auto ldG = [&](int g, float4& S) {     // t descending, clamped to 0
            int t0 = Te - 4 * g;
            int ta = t0 > 0 ? t0 : 0, tb2 = t0 - 1 > 0 ? t0 - 1 : 0;
            int tc = t0 - 2 > 0 ? t0 - 2 : 0, td = t0 - 3 > 0 ? t0 - 3 : 0;
            S.x = (lp + ((size_t)ta << 16))[idx];
            S.y = (lp + ((size_t)tb2 << 16))[idx];
            S.z = (lp + ((size_t)tc << 16))[idx];
            S.w = (lp + ((size_t)td << 16))[idx];
        };
        auto shl1 = [&](float x) -> float {    // lane i <- x[i+1]; lane 63 <- NEGF
            float v16 = rlane(x, 16), v32 = rlane(x, 32), v48 = rlane(x, 48);
            float bval = is15 ? v16 : (is31 ? v32 : (is47 ? v48 : NEGF));
            return __int_as_float(__builtin_amdgcn_update_dpp(
                __float_as_int(bval), __float_as_int(x), 0x101, 0xF, 0xF, false));
        };
        // beta step (em at t+1): B0' = lae(xb+B0, xe+B1);
        // B1' = lae(xe+B1, shl1(skip1 ? B0'(has both succ terms) : xb+B0)).
        auto stepb = [&](float xb, float xe) {
            float z = B1 + xe;
            float t0v = B0 + xb;
            float d0 = t0v - z;
            float m0 = fmaxf(t0v, z);
            float u = ex2(-fabsf(d0));
            float h = fmaf(u, P2C, P1C);
            h = fmaf(u, h, P0C);
            float B0n = fmaf(u, h, m0);        // lae2(t0v, z)
            float y = skip1 ? B0n : t0v;
            float arg = shl1(y);
            float d1 = z - arg;
            float m1 = fmaxf(z, arg);
            float v = ex2(-fabsf(d1));
            float h1 = fmaf(v, P2C, P1C);
            h1 = fmaf(v, h1, P0C);
            float B1n = fmaf(v, h1, m1);       // lae2(z, arg)
            B0 = B0n; B1 = B1n;
        };
        if (K >= 35) {
            float4 S0, S1, S2, S3, S4, S5, S6, S7;
            ldG(0, S0); ldG(1, S1); ldG(2, S2); ldG(3, S3);
            ldG(4, S4); ldG(5, S5); ldG(6, S6); ldG(7, S7);
            FENCE_;
#define SUBF_B(S, G) do {                                                      \
            float e0_ = S.x * LOG2E_, e1_ = S.y * LOG2E_;                      \
            float e2_ = S.z * LOG2E_, e3_ = S.w * LOG2E_;                      \
            float b0_ = rlane(e0_, 63), b1_ = rlane(e1_, 63);                  \
            float b2_ = rlane(e2_, 63), b3_ = rlane(e3_, 63);                  \
            stepb(b0_, e0_); stepb(b1_, e1_); stepb(b2_, e2_); stepb(b3_, e3_);\
            ldG((G) + 8, S);                                                   \
            FENCE_;                                                            \
        } while (0)
            SUBF_B(S0, 0); SUBF_B(S1, 1); SUBF_B(S2, 2); SUBF_B(S3, 3);
            SUBF_B(S4, 4); SUBF_B(S5, 5); SUBF_B(S6, 6); SUBF_B(S7, 7);
            int c = 1;
            for (; 32 * c + 31 <= K - 1; ++c) {
                int g0 = 8 * c;
                SUBF_B(S0, g0 + 0); SUBF_B(S1, g0 + 1); SUBF_B(S2, g0 + 2); SUBF_B(S3, g0 + 3);
                SUBF_B(S4, g0 + 4); SUBF_B(S5, g0 + 5); SUBF_B(S6, g0 + 6); SUBF_B(S7, g0 + 7);
            }
#undef SUBF_B
            int kb = 32 * c;
#define SUBT_B(S, K0) do {                                                     \
            float e0_ = S.x * LOG2E_, e1_ = S.y * LOG2E_;                      \
            float e2_ = S.z * LOG2E_, e3_ = S.w * LOG2E_;                      \
            float b0_ = rlane(e0_, 63), b1_ = rlane(e1_, 63);                  \
            float b2_ = rlane(e2_, 63), b3_ = rlane(e3_, 63);                  \
            if ((K0) + 0 <= K - 1) stepb(b0_, e0_);                            \
            if ((K0) + 1 <= K - 1) stepb(b1_, e1_);                            \
            if ((K0) + 2 <= K - 1) stepb(b2_, e2_);                            \
            if ((K0) + 3 <= K - 1) stepb(b3_, e3_);                            \
        } while (0)
            SUBT_B(S0, kb + 0);  SUBT_B(S1, kb + 4);  SUBT_B(S2, kb + 8);  SUBT_B(S3, kb + 12);
            SUBT_B(S4, kb + 16); SUBT_B(S5, kb + 20); SUBT_B(S6, kb + 24); SUBT_B(S7, kb + 28);
#undef SUBT_B
        } else {
            for (int k = 0; k < K; ++k) {
                int t = Te - k;
                float xe = (lp + ((size_t)t << 16))[idx] * LOG2E_;
                stepb(rlane(xe, 63), xe);
            }
        }
        awb[128 + lane] = B0;
        awb[192 + lane] = B1;
    }
}

// Per-sample junction combine: fin = lae over 128 states of (alpha_M + beta_M).
__global__ __launch_bounds__(64) void combine_k(const float* __restrict__ aw,
                                                const int* __restrict__ tlen,
                                                const int* __restrict__ ilen,
                                                float* __restrict__ losses) {
    int b = blockIdx.x, lane = threadIdx.x;
    const float* awb = aw + b * 256;
    float s0 = awb[lane] + awb[128 + lane];
    float s1 = awb[64 + lane] + awb[192 + lane];
    float m = fmaxf(s0, s1);
    for (int off = 32; off; off >>= 1) m = fmaxf(m, __shfl_xor(m, off));
    float sum = ex2(s0 - m) + ex2(s1 - m);
    for (int off = 32; off; off >>= 1) sum += __shfl_xor(sum, off);
    if (lane == 0) {
        int L = tlen[b];
        float fin = lg2(sum) + m;                  // log2 domain
        if (ilen[b] <= 0) fin = NEGF;
        float loss = (L > 0) ? -fin * LN2_ : 0.0f;
        if (!(loss < 1e29f)) loss = 0.0f;          // zero_infinity (NaN-safe)
        losses[b] = loss;
    }
}

// Fallback when ws too small: fully serial per-sample forward straight from lp.
__global__ __launch_bounds__(64) void ctc_rec_direct_k(const float* __restrict__ lp,
                                                       const int* __restrict__ targets,
                                                       const int* __restrict__ tlen,
                                                       const int* __restrict__ ilen,
                                                       float* __restrict__ losses) {
    int b = blockIdx.x, lane = threadIdx.x;
    int tg, L;
    load_tgt(targets, tlen, b, lane, tg, L);
    int Tin = ilen[b], Te = Tin - 1;
    int tgp = __shfl_up(tg, 1);
    bool skip1 = (lane >= 1) && (tg != 0) && (tg != tgp);
    bool is16 = (lane == 16), is32 = (lane == 32), is48 = (lane == 48);
    int col = (lane == 63) ? 0 : tg;
    int idx = (b << 10) + col;
    float a0 = NEGF, a1 = NEGF;
    auto shr1 = [&](float x) -> float {
        float v15 = rlane(x, 15), v31 = rlane(x, 31), v47 = rlane(x, 47);
        float bval = is16 ? v15 : (is32 ? v31 : (is48 ? v47 : NEGF));
        return __int_as_float(__builtin_amdgcn_update_dpp(
            __float_as_int(bval), __float_as_int(x), 0x111, 0xF, 0xF, false));
    };
    auto step = [&](float xb, float xe) {
        float p1m = shr1(a1);
        float d0 = a0 - p1m;
        float m0 = fmaxf(a0, p1m);
        float u = ex2(-fabsf(d0));
        float h = fmaf(u, P2C, P1C);
        h = fmaf(u, h, P0C);
        float U = fmaf(u, h, m0);
        float na0 = U + xb;
        float w = skip1 ? U : a0;
        float d1 = a1 - w;
        float m1 = fmaxf(a1, w);
        float v = ex2(-fabsf(d1));
        float h1 = fmaf(v, P2C, P1C);
        h1 = fmaf(v, h1, P0C);
        float na1 = fmaf(v, h1, m1 + xe);
        a0 = na0; a1 = na1;
    };
    if (Tin >= 1) {
        float e = lp[idx] * LOG2E_;
        a0 = (lane == 0) ? rlane(e, 63) : NEGF;
        a1 = (lane == 0 && L > 0) ? e : NEGF;
        for (int t = 1; t <= Te; ++t) {
            float xe = (lp + ((size_t)t << 16))[idx] * LOG2E_;
            step(rlane(xe, 63), xe);
        }
    }
    int lidx = (L > 0) ? (L - 1) : 0;
    float aPrev = __shfl(a1, lidx);
    float aLast = __shfl(a0, (L < 63) ? L : 63);
    float x = aLast, y = (L > 0) ? aPrev : NEGF;
    float m = fmaxf(x, y), d = fminf(x, y) - m;
    float fin = m + lg2(1.0f + ex2(d));
    if (Tin <= 0) fin = NEGF;
    if (lane == 0) {
        float loss = (L > 0) ? -fin * LN2_ : 0.0f;
        if (!(loss < 1e29f)) loss = 0.0f;
        losses[b] = loss;
    }
}

__global__ __launch_bounds__(64) void finalize_k(const float* __restrict__ losses,
                                                 const int* __restrict__ gid,
                                                 float* __restrict__ out) {
    int lane = threadIdx.x;
    float l = losses[lane];
    int g = gid[lane];
    float s = l;
    float s0 = (g == 0) ? l : 0.0f, c0 = (g == 0) ? 1.0f : 0.0f;
    float s1 = (g == 1) ? l : 0.0f, c1 = (g == 1) ? 1.0f : 0.0f;
    for (int off = 32; off; off >>= 1) {
        s  += __shfl_xor(s, off);
        s0 += __shfl_xor(s0, off);
        c0 += __shfl_xor(c0, off);
        s1 += __shfl_xor(s1, off);
        c1 += __shfl_xor(c1, off);
    }
    if (lane == 0) {
        float base = s * (1.0f / B_);
        float m0 = s0 / fmaxf(c0, 1.0f);
        float m1 = s1 / fmaxf(c1, 1.0f);
        float mean = 0.5f * (m0 + m1);
        float var = (m0 - mean) * (m0 - mean) + (m1 - mean) * (m1 - mean); // ddof=1, N=2
        out[0] = base + 0.5f * var;
        out[1] = base;
        out[2] = var;
    }
}

extern "C" void kernel_launch(void* const* d_in, const int* in_sizes, int n_in,
                              void* d_out, int out_size, void* d_ws, size_t ws_size,
                              hipStream_t stream) {
    const float* lp = (const float*)d_in[0];
    const int* targets = (const int*)d_in[1];
    const int* ilen = (const int*)d_in[2];
    const int* tlen = (const int*)d_in[3];
    const int* gid = (const int*)d_in[4];
    float* out = (float*)d_out;

    char* ws = (char*)d_ws;
    float* losses = (float*)ws;                       // 256 B
    float* aw = (float*)(ws + 1024);                  // 64*256*4 = 64 KB
    size_t need = 1024 + (size_t)B_ * 256 * 4;

    if (ws_size >= need) {
        ctc_fb_k<<<2 * B_, 64, 0, stream>>>(lp, targets, tlen, ilen, aw);
        combine_k<<<B_, 64, 0, stream>>>(aw, tlen, ilen, losses);
    } else {
        ctc_rec_direct_k<<<B_, 64, 0, stream>>>(lp, targets, tlen, ilen, losses);
    }
    finalize_k<<<1, 64, 0, stream>>>(losses, gid, out);
}